// Round 10
// baseline (214.487 us; speedup 1.0000x reference)
//
#include <hip/hip_runtime.h>
#include <hip/hip_bf16.h>

#define DD 128
#define EPSN 1e-12f
#define JSPLIT 8

typedef __attribute__((ext_vector_type(8))) short bf16x8;
typedef __attribute__((ext_vector_type(16))) float f32x16;

__device__ __forceinline__ unsigned short f2b(float f) {
  unsigned int u = __builtin_bit_cast(unsigned int, f);
  return (unsigned short)((u + 0x7fffu + ((u >> 16) & 1u)) >> 16);
}
__device__ __forceinline__ float b2f(unsigned short u) {
  unsigned int v = ((unsigned int)u) << 16;
  return __builtin_bit_cast(float, v);
}

// ---------------------------------------------------------------------------
// fp32 -> bf16: two big tensors (f1, f2).  grid(n4/256, 2)
// ---------------------------------------------------------------------------
__global__ __launch_bounds__(256) void k_cvt2(const float* __restrict__ a,
                                              const float* __restrict__ b,
                                              unsigned short* __restrict__ da,
                                              unsigned short* __restrict__ db,
                                              int n4) {
  int i = blockIdx.x * 256 + threadIdx.x;
  const float* s = blockIdx.y ? b : a;
  unsigned short* d = blockIdx.y ? db : da;
  if (i < n4) {
    float4 v = ((const float4*)s)[i];
    ushort4 o;
    o.x = f2b(v.x); o.y = f2b(v.y); o.z = f2b(v.z); o.w = f2b(v.w);
    ((ushort4*)d)[i] = o;
  }
}

// ---------------------------------------------------------------------------
// T = X^T X  (D x D, symmetric), atomic-accumulated.  grid(2,2,64) x 256
// PROVEN (rounds 1-5, 8).  Reads X fp32 directly.
// ---------------------------------------------------------------------------
__global__ __launch_bounds__(256) void k_ata(const float* __restrict__ X,
                                             float* __restrict__ T,
                                             int chunkRows) {
  __shared__ float si[128][64];
  __shared__ float sj[128][64];
  const int bi = blockIdx.x, bj = blockIdx.y;
  const int n0 = blockIdx.z * chunkRows;
  const int t = threadIdx.x;
  for (int idx = t; idx < 128 * 16; idx += 256) {
    int r = idx >> 4, c4 = idx & 15;
    float4 a = *((const float4*)(X + (size_t)(n0 + r) * DD + bi * 64) + c4);
    float4 b = *((const float4*)(X + (size_t)(n0 + r) * DD + bj * 64) + c4);
    *(float4*)&si[r][c4 * 4] = a;
    *(float4*)&sj[r][c4 * 4] = b;
  }
  __syncthreads();
  const int tx = t & 15, ty = t >> 4;
  float acc[4][4] = {};
  for (int n = 0; n < 128; ++n) {
    float4 av = *(const float4*)&si[n][ty * 4];
    float4 bv = *(const float4*)&sj[n][tx * 4];
    float a[4] = {av.x, av.y, av.z, av.w};
    float b[4] = {bv.x, bv.y, bv.z, bv.w};
#pragma unroll
    for (int i = 0; i < 4; ++i)
#pragma unroll
      for (int j = 0; j < 4; ++j) acc[i][j] += a[i] * b[j];
  }
#pragma unroll
  for (int i = 0; i < 4; ++i)
#pragma unroll
    for (int j = 0; j < 4; ++j)
      atomicAdd(&T[(size_t)(bi * 64 + ty * 4 + i) * DD + bj * 64 + tx * 4 + j],
                acc[i][j]);
}

// ---------------------------------------------------------------------------
// fp32 -> bf16: ten DxD matrices in one dispatch.  grid(16, 10)
// ---------------------------------------------------------------------------
__global__ __launch_bounds__(256) void k_cvt10(
    const float* __restrict__ s0, const float* __restrict__ s1,
    const float* __restrict__ s2, const float* __restrict__ s3,
    const float* __restrict__ s4, const float* __restrict__ s5,
    const float* __restrict__ s6, const float* __restrict__ s7,
    const float* __restrict__ s8, const float* __restrict__ s9,
    unsigned short* __restrict__ d0, unsigned short* __restrict__ d1,
    unsigned short* __restrict__ d2, unsigned short* __restrict__ d3,
    unsigned short* __restrict__ d4, unsigned short* __restrict__ d5,
    unsigned short* __restrict__ d6, unsigned short* __restrict__ d7,
    unsigned short* __restrict__ d8, unsigned short* __restrict__ d9) {
  int i = blockIdx.x * 256 + threadIdx.x;
  const float* s;
  unsigned short* d;
  switch (blockIdx.y) {
    case 0: s = s0; d = d0; break;
    case 1: s = s1; d = d1; break;
    case 2: s = s2; d = d2; break;
    case 3: s = s3; d = d3; break;
    case 4: s = s4; d = d4; break;
    case 5: s = s5; d = d5; break;
    case 6: s = s6; d = d6; break;
    case 7: s = s7; d = d7; break;
    case 8: s = s8; d = d8; break;
    default: s = s9; d = d9; break;
  }
  float4 v = ((const float4*)s)[i];
  ushort4 o;
  o.x = f2b(v.x); o.y = f2b(v.y); o.z = f2b(v.z); o.w = f2b(v.w);
  ((ushort4*)d)[i] = o;
}

// ---------------------------------------------------------------------------
// MFMA fused attention (R4-exact: proven 46.6us).  Atomic f32 HA + rabs.
// Static LDS = exactly 64KB.  grid(N/128, JSPLIT) x 512.
// ---------------------------------------------------------------------------
__global__ __launch_bounds__(512, 2) void k_attn(
    const unsigned short* __restrict__ Xb, const unsigned short* __restrict__ Yb,
    float* __restrict__ HA, float* __restrict__ rabs, int N) {
  __shared__ __align__(16) char LP[65536];
  unsigned short* Yst = (unsigned short*)LP;  // [2][10240] tr-subtiles (40KB)
  float* mrg = (float*)LP;                    // epilogue merge [4][32][128] 64KB
  const int t = threadIdx.x;
  const int w = t >> 6, l = t & 63, lh = l >> 5, ln = l & 31;
  const int wb = w >> 1, jh = w & 1;
  const int i0 = blockIdx.x * 128;
  const int jbase = blockIdx.y * (N / JSPLIT);
  const int jiters = (N / JSPLIT) / 64;

  // X fragments in registers (loop-invariant)
  const int xrow = i0 + wb * 32 + ln;
  bf16x8 xf[8];
#pragma unroll
  for (int kc = 0; kc < 8; ++kc)
    xf[kc] = *(const bf16x8*)(Xb + (size_t)xrow * DD + kc * 16 + lh * 8);

  f32x16 acc2[4];
#pragma unroll
  for (int cb = 0; cb < 4; ++cb)
#pragma unroll
    for (int r = 0; r < 16; ++r) acc2[cb][r] = 0.f;
  float rsum = 0.f;

  // staging: thread t -> row sjj, chunks ch0, ch0+8
  const int sjj = t >> 3;
  const int ch0 = t & 7;
  const int SB = sjj >> 2;
  bf16x8 rg[2];
  {
    const unsigned short* yb = Yb + (size_t)(jbase + sjj) * DD + ch0 * 8;
    rg[0] = *(const bf16x8*)yb;
    rg[1] = *(const bf16x8*)(yb + 64);
  }
#pragma unroll
  for (int c = 0; c < 2; ++c) {
    int ch = ch0 + 8 * c;
    int blk = SB * 8 + ((ch >> 1) ^ (SB & 7));
    int eoff = 80 * blk + (sjj & 3) * 16 + (((ch & 1) ^ (SB & 1)) << 3);
    *(bf16x8*)&Yst[eoff] = rg[c];
  }

  const unsigned ystBase0 = (unsigned)(size_t)Yst;
  const int d4b = ln >> 4;
  const int xrb = (ln & 15) << 1;
  const int yr = jh * 32 + ln;
  const int YB = yr >> 2;

  for (int jt = 0; jt < jiters; ++jt) {
    const int cur = jt & 1;
    __syncthreads();  // buf[cur] writes visible; prev readers done
    // T14: prefetch next Y tile into regs
    if (jt + 1 < jiters) {
      const unsigned short* yb =
          Yb + (size_t)(jbase + (jt + 1) * 64 + sjj) * DD + ch0 * 8;
      rg[0] = *(const bf16x8*)yb;
      rg[1] = *(const bf16x8*)(yb + 64);
    }
    // ---- ph1 (swapped): lane ln holds S-row i; two MFMA chains
    f32x16 s0, s1;
#pragma unroll
    for (int r = 0; r < 16; ++r) { s0[r] = 0.f; s1[r] = 0.f; }
#pragma unroll
    for (int kc = 0; kc < 8; ++kc) {
      int ck = kc * 2 + lh;
      int off = 80 * (YB * 8 + ((ck >> 1) ^ (YB & 7))) + (yr & 3) * 16 +
                (((ck & 1) ^ (YB & 1)) << 3);
      bf16x8 yv = *(const bf16x8*)&Yst[cur * 10240 + off];
      if (kc & 1)
        s1 = __builtin_amdgcn_mfma_f32_32x32x16_bf16(yv, xf[kc], s1, 0, 0, 0);
      else
        s0 = __builtin_amdgcn_mfma_f32_32x32x16_bf16(yv, xf[kc], s0, 0, 0, 0);
    }
    f32x16 s;
#pragma unroll
    for (int r = 0; r < 16; ++r) s[r] = s0[r] + s1[r];
    // ---- diag zero (tile-on-diagonal only)
    const int j0g = jbase + jt * 64 + jh * 32;
    if (i0 + wb * 32 == j0g) {
#pragma unroll
      for (int r = 0; r < 16; ++r) {
        int jl = (r & 3) + 8 * (r >> 2) + 4 * lh;
        if (jl == ln) s[r] = 0.f;
      }
    }
    // ---- rowabs (lane-local row)
#pragma unroll
    for (int r = 0; r < 16; ++r) rsum += fabsf(s[r]);
    // ---- issue ph2 B tr-reads
    const unsigned yB = ystBase0 + (unsigned)(cur * 20480);
    uint2 tvv[2][4][2];
#pragma unroll
    for (int f = 0; f < 2; ++f)
#pragma unroll
      for (int h2 = 0; h2 < 2; ++h2) {
        const int B = jh * 8 + f * 4 + lh * 2 + h2;
        const int b7 = B & 7;
        const unsigned xr2 = (unsigned)(xrb ^ (h2 << 4));
#pragma unroll
        for (int cb = 0; cb < 4; ++cb) {
          int blk = B * 8 + ((cb * 2 + d4b) ^ b7);
          unsigned a = yB + (unsigned)(blk * 160) + xr2;
          asm volatile("ds_read_b64_tr_b16 %0, %1"
                       : "=v"(tvv[f][cb][h2])
                       : "v"(a));
        }
      }
    // ---- pack S row to bf16 fragments (cvt_pk + permlane32_swap)
    unsigned pq[8];
#pragma unroll
    for (int q = 0; q < 8; ++q)
      asm("v_cvt_pk_bf16_f32 %0, %1, %2"
          : "=v"(pq[q])
          : "v"(s[2 * q]), "v"(s[2 * q + 1]));
    bf16x8 av2[2];
#pragma unroll
    for (int f = 0; f < 2; ++f) {
      unsigned a0 = pq[4 * f + 0], b0 = pq[4 * f + 2];
      unsigned a1 = pq[4 * f + 1], b1 = pq[4 * f + 3];
      asm volatile("v_permlane32_swap_b32 %0, %1" : "+v"(a0), "+v"(b0));
      asm volatile("v_permlane32_swap_b32 %0, %1" : "+v"(a1), "+v"(b1));
      av2[f] = __builtin_bit_cast(bf16x8, make_uint4(a0, a1, b0, b1));
    }
    // ---- drain tr reads, fence, ph2 MFMAs (rule #18)
    asm volatile("s_waitcnt lgkmcnt(0)" ::: "memory");
    __builtin_amdgcn_sched_barrier(0);
#pragma unroll
    for (int f = 0; f < 2; ++f)
#pragma unroll
      for (int cb = 0; cb < 4; ++cb) {
        bf16x8 bv = __builtin_bit_cast(
            bf16x8, make_uint4(tvv[f][cb][0].x, tvv[f][cb][0].y,
                               tvv[f][cb][1].x, tvv[f][cb][1].y));
        acc2[cb] =
            __builtin_amdgcn_mfma_f32_32x32x16_bf16(av2[f], bv, acc2[cb], 0, 0, 0);
      }
    // ---- write prefetched regs -> buf[cur^1]
    if (jt + 1 < jiters) {
      int bo = (cur ^ 1) * 10240;
#pragma unroll
      for (int c = 0; c < 2; ++c) {
        int ch = ch0 + 8 * c;
        int blk = SB * 8 + ((ch >> 1) ^ (SB & 7));
        int eoff = bo + 80 * blk + (sjj & 3) * 16 + (((ch & 1) ^ (SB & 1)) << 3);
        *(bf16x8*)&Yst[eoff] = rg[c];
      }
    }
  }
  // ---- epilogue (R4-exact): merge j-halves in LDS, atomicAdd HA + rabs
  rsum += __shfl_xor(rsum, 32);
  __syncthreads();
  if (jh == 1) {
#pragma unroll
    for (int cb = 0; cb < 4; ++cb)
#pragma unroll
      for (int r = 0; r < 16; ++r) {
        int rl = (r & 3) + 8 * (r >> 2) + 4 * lh;
        mrg[wb * 4096 + rl * 128 + cb * 32 + ln] = acc2[cb][r];
      }
  }
  __syncthreads();
  if (jh == 0) {
#pragma unroll
    for (int cb = 0; cb < 4; ++cb)
#pragma unroll
      for (int r = 0; r < 16; ++r) {
        int rl = (r & 3) + 8 * (r >> 2) + 4 * lh;
        float v = acc2[cb][r] + mrg[wb * 4096 + rl * 128 + cb * 32 + ln];
        atomicAdd(&HA[(size_t)(i0 + wb * 32 + rl) * DD + cb * 32 + ln], v);
      }
  }
  if (l < 32) atomicAdd(&rabs[i0 + wb * 32 + ln], rsum);
}

// ---------------------------------------------------------------------------
// Fused post-attention chain, batched staging:
//  - direct f32 HA fragment reads (no slice-sum stage), rb scalar read
//  - T/Wm/Ws staged into 96KB 3-buffer LDS up front -> 3 GEMMs back-to-back
//  - Wg1/Wg2 restaged -> 2 GEMMs; ~6 barriers total
//  - self-zeroes its own HA rows + rb entries (replaces mid-chain memset)
// grid(N/32) x 256.  Static LDS ~115KB (gfx950 allows 160KB/workgroup).
// ---------------------------------------------------------------------------
__device__ __forceinline__ void stageW(const unsigned short* __restrict__ g,
                                       unsigned short (*L)[128], int t) {
#pragma unroll
  for (int idx = t; idx < 2048; idx += 256) {
    int r = idx >> 4, ch = idx & 15;
    *(bf16x8*)&L[r][(ch ^ (r & 15)) << 3] = *(const bf16x8*)(g + r * 128 + ch * 8);
  }
}
__device__ __forceinline__ bf16x8 wfrag(const unsigned short (*L)[128], int row,
                                        int kc, int lh) {
  int ch = kc * 2 + lh;
  return *(const bf16x8*)&L[row][(ch ^ (row & 15)) << 3];
}

__global__ __launch_bounds__(256) void k_post(
    float* __restrict__ HA, float* __restrict__ rb,
    const unsigned short* __restrict__ fselfb,
    const unsigned short* __restrict__ fbaseb,
    const unsigned short* __restrict__ Tb,
    const unsigned short* __restrict__ Wmb, const float* __restrict__ bm,
    const unsigned short* __restrict__ Wsb, const float* __restrict__ bs,
    const unsigned short* __restrict__ Wg1b, const float* __restrict__ bg1,
    const unsigned short* __restrict__ Wg2b, const float* __restrict__ bg2,
    float* __restrict__ outNorm, float* __restrict__ outValF,
    unsigned short* __restrict__ outValB, int N) {
  __shared__ unsigned short WLS[3][128][128];        // 96KB
  __shared__ __align__(16) char pool[32 * 132 * 4];  // Mb+Sb / tr alias
  __shared__ float blds[3][128];
  __shared__ float rowpart[4][32];
  unsigned short(*Mb)[128] = (unsigned short(*)[128])pool;
  unsigned short(*Sb)[128] = (unsigned short(*)[128])(pool + 8192);
  float(*tr)[132] = (float(*)[132])pool;

  const int t = threadIdx.x;
  const int w = t >> 6, l = t & 63, ln = l & 31, lh = l >> 5;
  const int i0 = blockIdx.x * 32;
  const int row = i0 + ln;
  const int cq = w;

  // ---- batched staging: T, Wm, Ws
  stageW(Tb, WLS[0], t);
  stageW(Wmb, WLS[1], t);
  stageW(Wsb, WLS[2], t);
  if (t < 128) {
    blds[0][t] = bm[t];
    blds[1][t] = bs[t];
    blds[2][t] = bg1[t] + bg2[t];
  }

  // ---- per-lane fragments (direct global reads; overlap staging latency)
  const float sc = (1.f / (float)N) / fmaxf(rb[row], EPSN);
  bf16x8 bfA[8], bfS[8], bfB[8];
#pragma unroll
  for (int kc = 0; kc < 8; ++kc) {
    const float* hp = HA + (size_t)row * DD + kc * 16 + lh * 8;
    float4 u = *(const float4*)hp;
    float4 v = *(const float4*)(hp + 4);
    bf16x8 a;
    a[0] = (short)f2b(u.x * sc); a[1] = (short)f2b(u.y * sc);
    a[2] = (short)f2b(u.z * sc); a[3] = (short)f2b(u.w * sc);
    a[4] = (short)f2b(v.x * sc); a[5] = (short)f2b(v.y * sc);
    a[6] = (short)f2b(v.z * sc); a[7] = (short)f2b(v.w * sc);
    bfA[kc] = a;
    bfS[kc] = *(const bf16x8*)(fselfb + (size_t)row * DD + kc * 16 + lh * 8);
    bfB[kc] = *(const bf16x8*)(fbaseb + (size_t)row * DD + kc * 16 + lh * 8);
  }
  __syncthreads();  // staging + all HA/rb reads complete

  // ---- self-zero own HA rows + rb (for next pass / next replay)
  for (int idx = t; idx < 1024; idx += 256) {
    int r = idx >> 5, c4 = idx & 31;
    *(float4*)&HA[(size_t)(i0 + r) * DD + c4 * 4] =
        make_float4(0.f, 0.f, 0.f, 0.f);
  }
  if (t < 32) rb[i0 + t] = 0.f;

  // ---- GEMM 1: basen = l1norm(T x fbase)
  f32x16 acc;
#pragma unroll
  for (int r = 0; r < 16; ++r) acc[r] = 0.f;
#pragma unroll
  for (int kc = 0; kc < 8; ++kc)
    acc = __builtin_amdgcn_mfma_f32_32x32x16_bf16(
        wfrag(WLS[0], cq * 32 + ln, kc, lh), bfB[kc], acc, 0, 0, 0);
  float sab = 0.f;
#pragma unroll
  for (int r = 0; r < 16; ++r) sab += fabsf(acc[r]);
  sab += __shfl_xor(sab, 32);
  if (l < 32) rowpart[w][ln] = sab;
  __syncthreads();
  const float rsum =
      rowpart[0][ln] + rowpart[1][ln] + rowpart[2][ln] + rowpart[3][ln];
  const float rinv = 1.f / fmaxf(rsum, EPSN);
  float basen[16];
#pragma unroll
  for (int r = 0; r < 16; ++r) basen[r] = acc[r] * rinv;

  // ---- GEMM 2: m = Wm x A  -> Mb
#pragma unroll
  for (int r = 0; r < 16; ++r) acc[r] = 0.f;
#pragma unroll
  for (int kc = 0; kc < 8; ++kc)
    acc = __builtin_amdgcn_mfma_f32_32x32x16_bf16(
        wfrag(WLS[1], cq * 32 + ln, kc, lh), bfA[kc], acc, 0, 0, 0);
#pragma unroll
  for (int r = 0; r < 16; ++r) {
    int c = cq * 32 + (r & 3) + 8 * (r >> 2) + 4 * lh;
    Mb[ln][(((c >> 3) ^ (ln & 15)) << 3) + (c & 7)] = f2b(acc[r] + blds[0][c]);
  }

  // ---- GEMM 3: s = Ws x fself -> Sb
#pragma unroll
  for (int r = 0; r < 16; ++r) acc[r] = 0.f;
#pragma unroll
  for (int kc = 0; kc < 8; ++kc)
    acc = __builtin_amdgcn_mfma_f32_32x32x16_bf16(
        wfrag(WLS[2], cq * 32 + ln, kc, lh), bfS[kc], acc, 0, 0, 0);
#pragma unroll
  for (int r = 0; r < 16; ++r) {
    int c = cq * 32 + (r & 3) + 8 * (r >> 2) + 4 * lh;
    Sb[ln][(((c >> 3) ^ (ln & 15)) << 3) + (c & 7)] = f2b(acc[r] + blds[1][c]);
  }
  __syncthreads();  // Mb/Sb visible; WLS[0..1] reads done

  // ---- restage Wg1, Wg2
  stageW(Wg1b, WLS[0], t);
  stageW(Wg2b, WLS[1], t);
  __syncthreads();

  // ---- GEMM 4+5: z = Wg1 x m + Wg2 x s
#pragma unroll
  for (int r = 0; r < 16; ++r) acc[r] = 0.f;
#pragma unroll
  for (int kc = 0; kc < 8; ++kc)
    acc = __builtin_amdgcn_mfma_f32_32x32x16_bf16(
        wfrag(WLS[0], cq * 32 + ln, kc, lh), wfrag(Mb, ln, kc, lh), acc, 0, 0, 0);
#pragma unroll
  for (int kc = 0; kc < 8; ++kc)
    acc = __builtin_amdgcn_mfma_f32_32x32x16_bf16(
        wfrag(WLS[1], cq * 32 + ln, kc, lh), wfrag(Sb, ln, kc, lh), acc, 0, 0, 0);

  // ---- gate epilogue
  float val[16];
#pragma unroll
  for (int r = 0; r < 16; ++r) {
    int c = cq * 32 + (r & 3) + 8 * (r >> 2) + 4 * lh;
    float z = acc[r] + blds[2][c];
    float g = 1.f / (1.f + __expf(-z));
    int off = (((c >> 3) ^ (ln & 15)) << 3) + (c & 7);
    float mv = b2f(Mb[ln][off]);
    float sv = b2f(Sb[ln][off]);
    val[r] = basen[r] + g * mv + (1.f - g) * sv;
  }

  const int orow = t >> 3, c0 = (t & 7) * 4;
  if (outNorm) {
    __syncthreads();
#pragma unroll
    for (int r = 0; r < 16; ++r)
      tr[ln][cq * 32 + (r & 3) + 8 * (r >> 2) + 4 * lh] = basen[r];
    __syncthreads();
#pragma unroll
    for (int q = 0; q < 4; ++q)
      *(float4*)&outNorm[(size_t)(i0 + orow) * DD + c0 + 32 * q] =
          *(const float4*)&tr[orow][c0 + 32 * q];
  }
  __syncthreads();
#pragma unroll
  for (int r = 0; r < 16; ++r)
    tr[ln][cq * 32 + (r & 3) + 8 * (r >> 2) + 4 * lh] = val[r];
  __syncthreads();
  if (outValF) {
#pragma unroll
    for (int q = 0; q < 4; ++q)
      *(float4*)&outValF[(size_t)(i0 + orow) * DD + c0 + 32 * q] =
          *(const float4*)&tr[orow][c0 + 32 * q];
  }
  if (outValB) {
#pragma unroll
    for (int q = 0; q < 4; ++q) {
      float4 v = *(const float4*)&tr[orow][c0 + 32 * q];
      ushort4 o;
      o.x = f2b(v.x); o.y = f2b(v.y); o.z = f2b(v.z); o.w = f2b(v.w);
      *(ushort4*)&outValB[(size_t)(i0 + orow) * DD + c0 + 32 * q] = o;
    }
  }
}

// ---------------------------------------------------------------------------
extern "C" void kernel_launch(void* const* d_in, const int* in_sizes, int n_in,
                              void* d_out, int out_size, void* d_ws,
                              size_t ws_size, hipStream_t stream) {
  const float* f1 = (const float*)d_in[0];
  const float* f2 = (const float*)d_in[1];
  const float* Wd1 = (const float*)d_in[2];
  const float* bd1 = (const float*)d_in[3];
  const float* Wd2 = (const float*)d_in[4];
  const float* bd2 = (const float*)d_in[5];
  const float* Ws1 = (const float*)d_in[6];
  const float* bs1 = (const float*)d_in[7];
  const float* Ws2 = (const float*)d_in[8];
  const float* bs2 = (const float*)d_in[9];
  const float* g1W1 = (const float*)d_in[10];
  const float* g1b1 = (const float*)d_in[11];
  const float* g1W2 = (const float*)d_in[12];
  const float* g1b2 = (const float*)d_in[13];
  const float* g2W1 = (const float*)d_in[14];
  const float* g2b1 = (const float*)d_in[15];
  const float* g2W2 = (const float*)d_in[16];
  const float* g2b2 = (const float*)d_in[17];

  const int N = in_sizes[0] / DD;  // 8192
  const size_t ND = (size_t)N * DD;

  float* ws = (float*)d_ws;
  float* T1 = ws;                                   // DD*DD f
  float* T2 = T1 + DD * DD;                         // DD*DD f
  float* HA = T2 + DD * DD;                         // ND f
  float* rb = HA + ND;                              // N f
  unsigned short* f1bb = (unsigned short*)(rb + N);
  unsigned short* f2bb = f1bb + ND;
  unsigned short* f1nb = f2bb + ND;
  unsigned short* T1b = f1nb + ND;
  unsigned short* T2b = T1b + DD * DD;
  unsigned short* Wb0 = T2b + DD * DD;
  unsigned short* Wb1 = Wb0 + DD * DD;
  unsigned short* Wb2 = Wb1 + DD * DD;
  unsigned short* Wb3 = Wb2 + DD * DD;
  unsigned short* Wb4 = Wb3 + DD * DD;
  unsigned short* Wb5 = Wb4 + DD * DD;
  unsigned short* Wb6 = Wb5 + DD * DD;
  unsigned short* Wb7 = Wb6 + DD * DD;
  float* out0 = (float*)d_out;
  float* out1 = out0 + ND;

  // one upfront memset: T1, T2, HA, rb (contiguous)
  hipMemsetAsync(T1, 0, sizeof(float) * (2 * DD * DD + ND + N), stream);

  // bf16 conversions
  k_cvt2<<<dim3((int)(ND / 4 / 256), 2), 256, 0, stream>>>(f1, f2, f1bb, f2bb,
                                                           (int)(ND / 4));
  // Gram matrices (proven atomic path) + weight/T conversions
  k_ata<<<dim3(2, 2, 64), 256, 0, stream>>>(f1, T1, N / 64);
  k_ata<<<dim3(2, 2, 64), 256, 0, stream>>>(f2, T2, N / 64);
  k_cvt10<<<dim3(16, 10), 256, 0, stream>>>(Wd1, Ws1, g1W1, g1W2, Wd2, Ws2,
                                            g2W1, g2W2, T1, T2, Wb0, Wb1, Wb2,
                                            Wb3, Wb4, Wb5, Wb6, Wb7, T1b, T2b);

  // --- message block 1: d2 -> d1 ---
  k_attn<<<dim3(N / 128, JSPLIT), 512, 0, stream>>>(f1bb, f2bb, HA, rb, N);
  k_post<<<N / 32, 256, 0, stream>>>(HA, rb, f2bb, f1bb, T1b, Wb0, bd1, Wb1,
                                     bs1, Wb2, g1b1, Wb3, g1b2, out0, nullptr,
                                     f1nb, N);

  // --- message block 2: d1 -> d2 ---
  k_attn<<<dim3(N / 128, JSPLIT), 512, 0, stream>>>(f2bb, f1nb, HA, rb, N);
  k_post<<<N / 32, 256, 0, stream>>>(HA, rb, f1nb, f2bb, T2b, Wb4, bd2, Wb5,
                                     bs2, Wb6, g2b1, Wb7, g2b2, nullptr, out1,
                                     nullptr, N);
}

// Round 11
// 175.683 us; speedup vs baseline: 1.2209x; 1.2209x over previous
//
#include <hip/hip_runtime.h>
#include <hip/hip_bf16.h>

#define DD 128
#define EPSN 1e-12f
#define JSPLIT 8

typedef __attribute__((ext_vector_type(8))) short bf16x8;
typedef __attribute__((ext_vector_type(16))) float f32x16;

__device__ __forceinline__ unsigned short f2b(float f) {
  unsigned int u = __builtin_bit_cast(unsigned int, f);
  return (unsigned short)((u + 0x7fffu + ((u >> 16) & 1u)) >> 16);
}
__device__ __forceinline__ float b2f(unsigned short u) {
  unsigned int v = ((unsigned int)u) << 16;
  return __builtin_bit_cast(float, v);
}

// ---------------------------------------------------------------------------
// fp32 -> bf16: two big tensors (f1, f2).  grid(n4/256, 2)
// ---------------------------------------------------------------------------
__global__ __launch_bounds__(256) void k_cvt2(const float* __restrict__ a,
                                              const float* __restrict__ b,
                                              unsigned short* __restrict__ da,
                                              unsigned short* __restrict__ db,
                                              int n4) {
  int i = blockIdx.x * 256 + threadIdx.x;
  const float* s = blockIdx.y ? b : a;
  unsigned short* d = blockIdx.y ? db : da;
  if (i < n4) {
    float4 v = ((const float4*)s)[i];
    ushort4 o;
    o.x = f2b(v.x); o.y = f2b(v.y); o.z = f2b(v.z); o.w = f2b(v.w);
    ((ushort4*)d)[i] = o;
  }
}

// ---------------------------------------------------------------------------
// T = X^T X  (D x D, symmetric), atomic-accumulated.  grid(2,2,64) x 256
// PROVEN (rounds 1-5, 8).  Reads X fp32 directly.
// ---------------------------------------------------------------------------
__global__ __launch_bounds__(256) void k_ata(const float* __restrict__ X,
                                             float* __restrict__ T,
                                             int chunkRows) {
  __shared__ float si[128][64];
  __shared__ float sj[128][64];
  const int bi = blockIdx.x, bj = blockIdx.y;
  const int n0 = blockIdx.z * chunkRows;
  const int t = threadIdx.x;
  for (int idx = t; idx < 128 * 16; idx += 256) {
    int r = idx >> 4, c4 = idx & 15;
    float4 a = *((const float4*)(X + (size_t)(n0 + r) * DD + bi * 64) + c4);
    float4 b = *((const float4*)(X + (size_t)(n0 + r) * DD + bj * 64) + c4);
    *(float4*)&si[r][c4 * 4] = a;
    *(float4*)&sj[r][c4 * 4] = b;
  }
  __syncthreads();
  const int tx = t & 15, ty = t >> 4;
  float acc[4][4] = {};
  for (int n = 0; n < 128; ++n) {
    float4 av = *(const float4*)&si[n][ty * 4];
    float4 bv = *(const float4*)&sj[n][tx * 4];
    float a[4] = {av.x, av.y, av.z, av.w};
    float b[4] = {bv.x, bv.y, bv.z, bv.w};
#pragma unroll
    for (int i = 0; i < 4; ++i)
#pragma unroll
      for (int j = 0; j < 4; ++j) acc[i][j] += a[i] * b[j];
  }
#pragma unroll
  for (int i = 0; i < 4; ++i)
#pragma unroll
    for (int j = 0; j < 4; ++j)
      atomicAdd(&T[(size_t)(bi * 64 + ty * 4 + i) * DD + bj * 64 + tx * 4 + j],
                acc[i][j]);
}

// ---------------------------------------------------------------------------
// fp32 -> bf16: ten DxD matrices in one dispatch.  grid(16, 10)
// ---------------------------------------------------------------------------
__global__ __launch_bounds__(256) void k_cvt10(
    const float* __restrict__ s0, const float* __restrict__ s1,
    const float* __restrict__ s2, const float* __restrict__ s3,
    const float* __restrict__ s4, const float* __restrict__ s5,
    const float* __restrict__ s6, const float* __restrict__ s7,
    const float* __restrict__ s8, const float* __restrict__ s9,
    unsigned short* __restrict__ d0, unsigned short* __restrict__ d1,
    unsigned short* __restrict__ d2, unsigned short* __restrict__ d3,
    unsigned short* __restrict__ d4, unsigned short* __restrict__ d5,
    unsigned short* __restrict__ d6, unsigned short* __restrict__ d7,
    unsigned short* __restrict__ d8, unsigned short* __restrict__ d9) {
  int i = blockIdx.x * 256 + threadIdx.x;
  const float* s;
  unsigned short* d;
  switch (blockIdx.y) {
    case 0: s = s0; d = d0; break;
    case 1: s = s1; d = d1; break;
    case 2: s = s2; d = d2; break;
    case 3: s = s3; d = d3; break;
    case 4: s = s4; d = d4; break;
    case 5: s = s5; d = d5; break;
    case 6: s = s6; d = d6; break;
    case 7: s = s7; d = d7; break;
    case 8: s = s8; d = d8; break;
    default: s = s9; d = d9; break;
  }
  float4 v = ((const float4*)s)[i];
  ushort4 o;
  o.x = f2b(v.x); o.y = f2b(v.y); o.z = f2b(v.z); o.w = f2b(v.w);
  ((ushort4*)d)[i] = o;
}

// ---------------------------------------------------------------------------
// MFMA fused attention (R8 structure, proven 47.6us) with ONE change:
// ph2 tr-reads issued at loop top (before ph1) — they depend only on the
// staged Y tile, so their LDS-pipe time hides under ph1's MFMAs.
// Static LDS = exactly 64KB.  grid(N/128, JSPLIT) x 512.
// ---------------------------------------------------------------------------
__global__ __launch_bounds__(512, 2) void k_attn(
    const unsigned short* __restrict__ Xb, const unsigned short* __restrict__ Yb,
    unsigned short* __restrict__ Hps, unsigned short* __restrict__ Hx,
    float* __restrict__ rbp, int N) {
  __shared__ __align__(16) char LP[65536];
  unsigned short* Yst = (unsigned short*)LP;   // [2][10240] tr-subtiles (40KB)
  unsigned short* mrgb = (unsigned short*)LP;  // epilogue [128][128] bf16 32KB
  float* rs = (float*)(LP + 32768);            // epilogue [4][32] rowabs merge
  const int t = threadIdx.x;
  const int w = t >> 6, l = t & 63, lh = l >> 5, ln = l & 31;
  const int wb = w >> 1, jh = w & 1;
  const int i0 = blockIdx.x * 128;
  const size_t ND = (size_t)N * DD;
  const int jbase = blockIdx.y * (N / JSPLIT);
  const int jiters = (N / JSPLIT) / 64;

  // X fragments in registers (loop-invariant)
  const int xrow = i0 + wb * 32 + ln;
  bf16x8 xf[8];
#pragma unroll
  for (int kc = 0; kc < 8; ++kc)
    xf[kc] = *(const bf16x8*)(Xb + (size_t)xrow * DD + kc * 16 + lh * 8);

  f32x16 acc2[4];
#pragma unroll
  for (int cb = 0; cb < 4; ++cb)
#pragma unroll
    for (int r = 0; r < 16; ++r) acc2[cb][r] = 0.f;
  float rsum = 0.f;

  // staging: thread t -> row sjj, chunks ch0, ch0+8
  const int sjj = t >> 3;
  const int ch0 = t & 7;
  const int SB = sjj >> 2;
  bf16x8 rg[2];
  {
    const unsigned short* yb = Yb + (size_t)(jbase + sjj) * DD + ch0 * 8;
    rg[0] = *(const bf16x8*)yb;
    rg[1] = *(const bf16x8*)(yb + 64);
  }
#pragma unroll
  for (int c = 0; c < 2; ++c) {
    int ch = ch0 + 8 * c;
    int blk = SB * 8 + ((ch >> 1) ^ (SB & 7));
    int eoff = 80 * blk + (sjj & 3) * 16 + (((ch & 1) ^ (SB & 1)) << 3);
    *(bf16x8*)&Yst[eoff] = rg[c];
  }

  const unsigned ystBase0 = (unsigned)(size_t)Yst;
  const int d4b = ln >> 4;
  const int xrb = (ln & 15) << 1;
  const int yr = jh * 32 + ln;
  const int YB = yr >> 2;

  for (int jt = 0; jt < jiters; ++jt) {
    const int cur = jt & 1;
    __syncthreads();  // buf[cur] writes visible; prev readers done
    // ---- EARLY: issue ph2 B tr-reads (depend only on staged tile)
    const unsigned yB = ystBase0 + (unsigned)(cur * 20480);
    uint2 tvv[2][4][2];
#pragma unroll
    for (int f = 0; f < 2; ++f)
#pragma unroll
      for (int h2 = 0; h2 < 2; ++h2) {
        const int B = jh * 8 + f * 4 + lh * 2 + h2;
        const int b7 = B & 7;
        const unsigned xr2 = (unsigned)(xrb ^ (h2 << 4));
#pragma unroll
        for (int cb = 0; cb < 4; ++cb) {
          int blk = B * 8 + ((cb * 2 + d4b) ^ b7);
          unsigned a = yB + (unsigned)(blk * 160) + xr2;
          asm volatile("ds_read_b64_tr_b16 %0, %1"
                       : "=v"(tvv[f][cb][h2])
                       : "v"(a));
        }
      }
    // T14: prefetch next Y tile into regs
    if (jt + 1 < jiters) {
      const unsigned short* yb =
          Yb + (size_t)(jbase + (jt + 1) * 64 + sjj) * DD + ch0 * 8;
      rg[0] = *(const bf16x8*)yb;
      rg[1] = *(const bf16x8*)(yb + 64);
    }
    // ---- ph1 (swapped): lane ln holds S-row i; two MFMA chains
    f32x16 s0, s1;
#pragma unroll
    for (int r = 0; r < 16; ++r) { s0[r] = 0.f; s1[r] = 0.f; }
#pragma unroll
    for (int kc = 0; kc < 8; ++kc) {
      int ck = kc * 2 + lh;
      int off = 80 * (YB * 8 + ((ck >> 1) ^ (YB & 7))) + (yr & 3) * 16 +
                (((ck & 1) ^ (YB & 1)) << 3);
      bf16x8 yv = *(const bf16x8*)&Yst[cur * 10240 + off];
      if (kc & 1)
        s1 = __builtin_amdgcn_mfma_f32_32x32x16_bf16(yv, xf[kc], s1, 0, 0, 0);
      else
        s0 = __builtin_amdgcn_mfma_f32_32x32x16_bf16(yv, xf[kc], s0, 0, 0, 0);
    }
    f32x16 s;
#pragma unroll
    for (int r = 0; r < 16; ++r) s[r] = s0[r] + s1[r];
    // ---- diag zero (tile-on-diagonal only)
    const int j0g = jbase + jt * 64 + jh * 32;
    if (i0 + wb * 32 == j0g) {
#pragma unroll
      for (int r = 0; r < 16; ++r) {
        int jl = (r & 3) + 8 * (r >> 2) + 4 * lh;
        if (jl == ln) s[r] = 0.f;
      }
    }
    // ---- rowabs (lane-local row)
#pragma unroll
    for (int r = 0; r < 16; ++r) rsum += fabsf(s[r]);
    // ---- pack S row to bf16 fragments (cvt_pk + permlane32_swap)
    unsigned pq[8];
#pragma unroll
    for (int q = 0; q < 8; ++q)
      asm("v_cvt_pk_bf16_f32 %0, %1, %2"
          : "=v"(pq[q])
          : "v"(s[2 * q]), "v"(s[2 * q + 1]));
    bf16x8 av2[2];
#pragma unroll
    for (int f = 0; f < 2; ++f) {
      unsigned a0 = pq[4 * f + 0], b0 = pq[4 * f + 2];
      unsigned a1 = pq[4 * f + 1], b1 = pq[4 * f + 3];
      asm volatile("v_permlane32_swap_b32 %0, %1" : "+v"(a0), "+v"(b0));
      asm volatile("v_permlane32_swap_b32 %0, %1" : "+v"(a1), "+v"(b1));
      av2[f] = __builtin_bit_cast(bf16x8, make_uint4(a0, a1, b0, b1));
    }
    // ---- drain tr reads, fence, ph2 MFMAs (rule #18)
    asm volatile("s_waitcnt lgkmcnt(0)" ::: "memory");
    __builtin_amdgcn_sched_barrier(0);
#pragma unroll
    for (int f = 0; f < 2; ++f)
#pragma unroll
      for (int cb = 0; cb < 4; ++cb) {
        bf16x8 bv = __builtin_bit_cast(
            bf16x8, make_uint4(tvv[f][cb][0].x, tvv[f][cb][0].y,
                               tvv[f][cb][1].x, tvv[f][cb][1].y));
        acc2[cb] =
            __builtin_amdgcn_mfma_f32_32x32x16_bf16(av2[f], bv, acc2[cb], 0, 0, 0);
      }
    // ---- write prefetched regs -> buf[cur^1]
    if (jt + 1 < jiters) {
      int bo = (cur ^ 1) * 10240;
#pragma unroll
      for (int c = 0; c < 2; ++c) {
        int ch = ch0 + 8 * c;
        int blk = SB * 8 + ((ch >> 1) ^ (SB & 7));
        int eoff = bo + 80 * blk + (sjj & 3) * 16 + (((ch & 1) ^ (SB & 1)) << 3);
        *(bf16x8*)&Yst[eoff] = rg[c];
      }
    }
  }
  // ---- epilogue: merge j-halves in LDS (bf16, aliases dead Yst)
  rsum += __shfl_xor(rsum, 32);
  __syncthreads();
  if (jh == 1) {
#pragma unroll
    for (int cb = 0; cb < 4; ++cb)
#pragma unroll
      for (int r = 0; r < 16; ++r) {
        int rl = (r & 3) + 8 * (r >> 2) + 4 * lh;
        mrgb[(wb * 32 + rl) * 128 + cb * 32 + ln] = f2b(acc2[cb][r]);
      }
    if (l < 32) rs[wb * 32 + ln] = rsum;
  }
  __syncthreads();
  if (jh == 0) {
    unsigned short* hp;
    int rstr;
    if (blockIdx.y < 6) {
      hp = Hps + (size_t)blockIdx.y * ND;
      rstr = 128;
    } else {
      hp = Hx + (blockIdx.y - 6) * 128;
      rstr = 256;
    }
#pragma unroll
    for (int cb = 0; cb < 4; ++cb)
#pragma unroll
      for (int r = 0; r < 16; ++r) {
        int rl = (r & 3) + 8 * (r >> 2) + 4 * lh;
        float v = acc2[cb][r] + b2f(mrgb[(wb * 32 + rl) * 128 + cb * 32 + ln]);
        hp[(size_t)(i0 + wb * 32 + rl) * rstr + cb * 32 + ln] = f2b(v);
      }
    if (l < 32)
      rbp[(size_t)blockIdx.y * N + i0 + wb * 32 + ln] = rsum + rs[wb * 32 + ln];
  }
}

// ---------------------------------------------------------------------------
// Fused post-attention chain (R8-exact); A-input = sum of 8 bf16 H-partial
// slices; rowabs = sum of 8 rbp slices.
// ---------------------------------------------------------------------------
__device__ __forceinline__ void stageW(const unsigned short* __restrict__ g,
                                       unsigned short (*L)[128], int t) {
#pragma unroll
  for (int idx = t; idx < 2048; idx += 256) {
    int r = idx >> 4, ch = idx & 15;
    *(bf16x8*)&L[r][(ch ^ (r & 15)) << 3] = *(const bf16x8*)(g + r * 128 + ch * 8);
  }
}
__device__ __forceinline__ bf16x8 wfrag(const unsigned short (*L)[128], int row,
                                        int kc, int lh) {
  int ch = kc * 2 + lh;
  return *(const bf16x8*)&L[row][(ch ^ (row & 15)) << 3];
}

__global__ __launch_bounds__(256) void k_post(
    const unsigned short* __restrict__ Hps, const unsigned short* __restrict__ Hx,
    const float* __restrict__ rbp, const unsigned short* __restrict__ fselfb,
    const unsigned short* __restrict__ fbaseb,
    const unsigned short* __restrict__ Tb,
    const unsigned short* __restrict__ Wmb, const float* __restrict__ bm,
    const unsigned short* __restrict__ Wsb, const float* __restrict__ bs,
    const unsigned short* __restrict__ Wg1b, const float* __restrict__ bg1,
    const unsigned short* __restrict__ Wg2b, const float* __restrict__ bg2,
    float* __restrict__ outNorm, float* __restrict__ outValF,
    unsigned short* __restrict__ outValB, int N) {
  __shared__ unsigned short WL[128][128];
  __shared__ __align__(16) char pool[32 * 132 * 4];
  __shared__ float blds[3][128];
  __shared__ float rowpart[4][32];
  unsigned short(*Mb)[128] = (unsigned short(*)[128])pool;
  unsigned short(*Sb)[128] = (unsigned short(*)[128])(pool + 8192);
  float(*tr)[132] = (float(*)[132])pool;
  float(*hs)[132] = (float(*)[132])pool;

  const int t = threadIdx.x;
  const int w = t >> 6, l = t & 63, ln = l & 31, lh = l >> 5;
  const int i0 = blockIdx.x * 32;
  const int row = i0 + ln;
  const int cq = w;
  const size_t ND = (size_t)N * DD;

  // ---- cooperative 8-slice sum -> hs (f32)
  for (int idx = t; idx < 512; idx += 256) {
    int r = idx >> 4, c8 = idx & 15;
    float a8[8] = {0.f, 0.f, 0.f, 0.f, 0.f, 0.f, 0.f, 0.f};
#pragma unroll
    for (int sp = 0; sp < 8; ++sp) {
      const unsigned short* p =
          (sp < 6) ? Hps + (size_t)sp * ND + (size_t)(i0 + r) * DD + c8 * 8
                   : Hx + (size_t)(i0 + r) * 256 + (sp - 6) * 128 + c8 * 8;
      bf16x8 v = *(const bf16x8*)p;
#pragma unroll
      for (int e = 0; e < 8; ++e) a8[e] += b2f((unsigned short)v[e]);
    }
    *(float4*)&hs[r][c8 * 8] = make_float4(a8[0], a8[1], a8[2], a8[3]);
    *(float4*)&hs[r][c8 * 8 + 4] = make_float4(a8[4], a8[5], a8[6], a8[7]);
  }
  if (t < 128) {
    blds[0][t] = bm[t];
    blds[1][t] = bs[t];
    blds[2][t] = bg1[t] + bg2[t];
  }
  stageW(Tb, WL, t);
  __syncthreads();

  // ---- per-lane fragments
  float rbv = 0.f;
#pragma unroll
  for (int sp = 0; sp < 8; ++sp) rbv += rbp[(size_t)sp * N + row];
  const float sc = (1.f / (float)N) / fmaxf(rbv, EPSN);
  bf16x8 bfA[8], bfS[8], bfB[8];
#pragma unroll
  for (int kc = 0; kc < 8; ++kc) {
    const float* hp = &hs[ln][kc * 16 + lh * 8];
    float4 u = *(const float4*)hp;
    float4 v = *(const float4*)(hp + 4);
    bf16x8 a;
    a[0] = (short)f2b(u.x * sc); a[1] = (short)f2b(u.y * sc);
    a[2] = (short)f2b(u.z * sc); a[3] = (short)f2b(u.w * sc);
    a[4] = (short)f2b(v.x * sc); a[5] = (short)f2b(v.y * sc);
    a[6] = (short)f2b(v.z * sc); a[7] = (short)f2b(v.w * sc);
    bfA[kc] = a;
    bfS[kc] = *(const bf16x8*)(fselfb + (size_t)row * DD + kc * 16 + lh * 8);
    bfB[kc] = *(const bf16x8*)(fbaseb + (size_t)row * DD + kc * 16 + lh * 8);
  }

  f32x16 acc;
#pragma unroll
  for (int r = 0; r < 16; ++r) acc[r] = 0.f;
#pragma unroll
  for (int kc = 0; kc < 8; ++kc)
    acc = __builtin_amdgcn_mfma_f32_32x32x16_bf16(
        wfrag(WL, cq * 32 + ln, kc, lh), bfB[kc], acc, 0, 0, 0);
  float sab = 0.f;
#pragma unroll
  for (int r = 0; r < 16; ++r) sab += fabsf(acc[r]);
  sab += __shfl_xor(sab, 32);
  if (l < 32) rowpart[w][ln] = sab;
  __syncthreads();
  const float rsum =
      rowpart[0][ln] + rowpart[1][ln] + rowpart[2][ln] + rowpart[3][ln];
  const float rinv = 1.f / fmaxf(rsum, EPSN);
  float basen[16];
#pragma unroll
  for (int r = 0; r < 16; ++r) basen[r] = acc[r] * rinv;

  stageW(Wmb, WL, t);
  __syncthreads();
#pragma unroll
  for (int r = 0; r < 16; ++r) acc[r] = 0.f;
#pragma unroll
  for (int kc = 0; kc < 8; ++kc)
    acc = __builtin_amdgcn_mfma_f32_32x32x16_bf16(
        wfrag(WL, cq * 32 + ln, kc, lh), bfA[kc], acc, 0, 0, 0);
#pragma unroll
  for (int r = 0; r < 16; ++r) {
    int c = cq * 32 + (r & 3) + 8 * (r >> 2) + 4 * lh;
    Mb[ln][(((c >> 3) ^ (ln & 15)) << 3) + (c & 7)] = f2b(acc[r] + blds[0][c]);
  }
  __syncthreads();

  stageW(Wsb, WL, t);
  __syncthreads();
#pragma unroll
  for (int r = 0; r < 16; ++r) acc[r] = 0.f;
#pragma unroll
  for (int kc = 0; kc < 8; ++kc)
    acc = __builtin_amdgcn_mfma_f32_32x32x16_bf16(
        wfrag(WL, cq * 32 + ln, kc, lh), bfS[kc], acc, 0, 0, 0);
#pragma unroll
  for (int r = 0; r < 16; ++r) {
    int c = cq * 32 + (r & 3) + 8 * (r >> 2) + 4 * lh;
    Sb[ln][(((c >> 3) ^ (ln & 15)) << 3) + (c & 7)] = f2b(acc[r] + blds[1][c]);
  }
  __syncthreads();

  stageW(Wg1b, WL, t);
  __syncthreads();
#pragma unroll
  for (int r = 0; r < 16; ++r) acc[r] = 0.f;
#pragma unroll
  for (int kc = 0; kc < 8; ++kc)
    acc = __builtin_amdgcn_mfma_f32_32x32x16_bf16(
        wfrag(WL, cq * 32 + ln, kc, lh), wfrag(Mb, ln, kc, lh), acc, 0, 0, 0);
  __syncthreads();
  stageW(Wg2b, WL, t);
  __syncthreads();
#pragma unroll
  for (int kc = 0; kc < 8; ++kc)
    acc = __builtin_amdgcn_mfma_f32_32x32x16_bf16(
        wfrag(WL, cq * 32 + ln, kc, lh), wfrag(Sb, ln, kc, lh), acc, 0, 0, 0);

  float val[16];
#pragma unroll
  for (int r = 0; r < 16; ++r) {
    int c = cq * 32 + (r & 3) + 8 * (r >> 2) + 4 * lh;
    float z = acc[r] + blds[2][c];
    float g = 1.f / (1.f + __expf(-z));
    int off = (((c >> 3) ^ (ln & 15)) << 3) + (c & 7);
    float mv = b2f(Mb[ln][off]);
    float sv = b2f(Sb[ln][off]);
    val[r] = basen[r] + g * mv + (1.f - g) * sv;
  }

  const int orow = t >> 3, c0 = (t & 7) * 4;
  if (outNorm) {
    __syncthreads();
#pragma unroll
    for (int r = 0; r < 16; ++r)
      tr[ln][cq * 32 + (r & 3) + 8 * (r >> 2) + 4 * lh] = basen[r];
    __syncthreads();
#pragma unroll
    for (int q = 0; q < 4; ++q)
      *(float4*)&outNorm[(size_t)(i0 + orow) * DD + c0 + 32 * q] =
          *(const float4*)&tr[orow][c0 + 32 * q];
  }
  __syncthreads();
#pragma unroll
  for (int r = 0; r < 16; ++r)
    tr[ln][cq * 32 + (r & 3) + 8 * (r >> 2) + 4 * lh] = val[r];
  __syncthreads();
  if (outValF) {
#pragma unroll
    for (int q = 0; q < 4; ++q)
      *(float4*)&outValF[(size_t)(i0 + orow) * DD + c0 + 32 * q] =
          *(const float4*)&tr[orow][c0 + 32 * q];
  }
  if (outValB) {
#pragma unroll
    for (int q = 0; q < 4; ++q) {
      float4 v = *(const float4*)&tr[orow][c0 + 32 * q];
      ushort4 o;
      o.x = f2b(v.x); o.y = f2b(v.y); o.z = f2b(v.z); o.w = f2b(v.w);
      *(ushort4*)&outValB[(size_t)(i0 + orow) * DD + c0 + 32 * q] = o;
    }
  }
}

// ---------------------------------------------------------------------------
extern "C" void kernel_launch(void* const* d_in, const int* in_sizes, int n_in,
                              void* d_out, int out_size, void* d_ws,
                              size_t ws_size, hipStream_t stream) {
  const float* f1 = (const float*)d_in[0];
  const float* f2 = (const float*)d_in[1];
  const float* Wd1 = (const float*)d_in[2];
  const float* bd1 = (const float*)d_in[3];
  const float* Wd2 = (const float*)d_in[4];
  const float* bd2 = (const float*)d_in[5];
  const float* Ws1 = (const float*)d_in[6];
  const float* bs1 = (const float*)d_in[7];
  const float* Ws2 = (const float*)d_in[8];
  const float* bs2 = (const float*)d_in[9];
  const float* g1W1 = (const float*)d_in[10];
  const float* g1b1 = (const float*)d_in[11];
  const float* g1W2 = (const float*)d_in[12];
  const float* g1b2 = (const float*)d_in[13];
  const float* g2W1 = (const float*)d_in[14];
  const float* g2b1 = (const float*)d_in[15];
  const float* g2W2 = (const float*)d_in[16];
  const float* g2b2 = (const float*)d_in[17];

  const int N = in_sizes[0] / DD;  // 8192
  const size_t ND = (size_t)N * DD;

  float* ws = (float*)d_ws;
  float* T1 = ws;                                   // DD*DD f
  float* T2 = T1 + DD * DD;                         // DD*DD f
  float* rbp = T2 + DD * DD;                        // 8*N f
  unsigned short* f1bb = (unsigned short*)(rbp + 8 * (size_t)N);
  unsigned short* f2bb = f1bb + ND;
  unsigned short* f1nb = f2bb + ND;
  unsigned short* T1b = f1nb + ND;
  unsigned short* T2b = T1b + DD * DD;
  unsigned short* Wb0 = T2b + DD * DD;
  unsigned short* Wb1 = Wb0 + DD * DD;
  unsigned short* Wb2 = Wb1 + DD * DD;
  unsigned short* Wb3 = Wb2 + DD * DD;
  unsigned short* Wb4 = Wb3 + DD * DD;
  unsigned short* Wb5 = Wb4 + DD * DD;
  unsigned short* Wb6 = Wb5 + DD * DD;
  unsigned short* Wb7 = Wb6 + DD * DD;
  unsigned short* Hps = Wb7 + DD * DD;              // 6*ND shorts
  float* out0 = (float*)d_out;
  float* out1 = out0 + ND;

  // bf16 conversions
  k_cvt2<<<dim3((int)(ND / 4 / 256), 2), 256, 0, stream>>>(f1, f2, f1bb, f2bb,
                                                           (int)(ND / 4));
  // Gram matrices (proven atomic path) + weight/T conversions
  hipMemsetAsync(T1, 0, sizeof(float) * 2 * DD * DD, stream);
  k_ata<<<dim3(2, 2, 64), 256, 0, stream>>>(f1, T1, N / 64);
  k_ata<<<dim3(2, 2, 64), 256, 0, stream>>>(f2, T2, N / 64);
  k_cvt10<<<dim3(16, 10), 256, 0, stream>>>(Wd1, Ws1, g1W1, g1W2, Wd2, Ws2,
                                            g2W1, g2W2, T1, T2, Wb0, Wb1, Wb2,
                                            Wb3, Wb4, Wb5, Wb6, Wb7, T1b, T2b);

  // --- message block 1: d2 -> d1 ---
  k_attn<<<dim3(N / 128, JSPLIT), 512, 0, stream>>>(
      f1bb, f2bb, Hps, (unsigned short*)out0, rbp, N);
  k_post<<<N / 32, 256, 0, stream>>>(Hps, (unsigned short*)out0, rbp, f2bb,
                                     f1bb, T1b, Wb0, bd1, Wb1, bs1, Wb2, g1b1,
                                     Wb3, g1b2, out0, nullptr, f1nb, N);

  // --- message block 2: d1 -> d2 ---
  k_attn<<<dim3(N / 128, JSPLIT), 512, 0, stream>>>(
      f2bb, f1nb, Hps, (unsigned short*)out1, rbp, N);
  k_post<<<N / 32, 256, 0, stream>>>(Hps, (unsigned short*)out1, rbp, f1nb,
                                     f2bb, T2b, Wb4, bd2, Wb5, bs2, Wb6, g2b1,
                                     Wb7, g2b2, nullptr, out1, nullptr, N);
}